// Round 3
// baseline (402.766 us; speedup 1.0000x reference)
//
#include <hip/hip_runtime.h>
#include <math.h>

#define NN 8192
#define CC 4096
#define SLOTS 64
#define BLK 256
#define NSPLIT 4     // 4 column splits of 1024 cols (4 KB) per class; one WAVE per (class,split)
#define NF4 (CC / 4) // 1024 float4 per feature row

// out = sum_c cnt_c * value_c * NUM_POS / N^2 ; NUM_POS=4, N=8192
#define SCALE (4.0f / (8192.0f * 8192.0f))

// Fused init + index build: one block, counts histogram in LDS (16 KB),
// LDS atomics for slot assignment, then flush counts and zero done-counter.
__global__ __launch_bounds__(1024) void build_kernel(const int* __restrict__ label,
                                                     int* __restrict__ counts,
                                                     int* __restrict__ lists,
                                                     unsigned* __restrict__ done) {
    __shared__ int s_cnt[CC];
    int t = threadIdx.x;
    #pragma unroll
    for (int i = t; i < CC; i += 1024) s_cnt[i] = 0;
    if (t == 0) *done = 0u;
    __syncthreads();
    #pragma unroll
    for (int i = t; i < NN; i += 1024) {
        int lab = label[i];
        int pos = atomicAdd(&s_cnt[lab], 1);
        if (pos < SLOTS) lists[lab * SLOTS + pos] = i;
    }
    __syncthreads();
    #pragma unroll
    for (int i = t; i < CC; i += 1024) counts[i] = s_cnt[i];
}

// Tiered gather: T rows x 4 float4 slots, all loads issued back-to-back
// (single vmcnt drain). Tail rows duplicate row 0 with weight 0 (dup loads
// hit L1 -- same addresses as k=0 -- ~free).
template <int T>
__device__ inline void gather4(const float4* __restrict__ feat4,
                               const int* __restrict__ rl, int m,
                               int slot, float4 acc[4]) {
    int r0 = rl[0];
    float4 v[T][4];
    #pragma unroll
    for (int k = 0; k < T; ++k) {
        int r = (k < m) ? rl[k] : r0;
        size_t rb = (size_t)r * NF4 + slot;
        #pragma unroll
        for (int j = 0; j < 4; ++j) v[k][j] = feat4[rb + j * 64];
    }
    #pragma unroll
    for (int k = 0; k < T; ++k) {
        float w = (k < m) ? 1.f : 0.f;
        #pragma unroll
        for (int j = 0; j < 4; ++j) {
            acc[j].x += w * v[k][j].x; acc[j].y += w * v[k][j].y;
            acc[j].z += w * v[k][j].z; acc[j].w += w * v[k][j].w;
        }
    }
}

// One block per class c; wave wv = split s (4 splits of 1024 cols). Lane l owns
// float4 slots s*256 + l + 64j (j=0..3): 4 coalesced 1 KB wave-loads per row,
// and the block's 4 waves together fetch each row as one 16 KB burst.
// The split-LSE merge is 3 scalars/wave through LDS (gather stays
// wave-independent). Last block (done-counter) reduces contrib[] -> out[0].
__global__ __launch_bounds__(BLK) void part_kernel(const float4* __restrict__ feat4,
                                                   const int* __restrict__ counts,
                                                   const int* __restrict__ lists,
                                                   float* __restrict__ contrib,
                                                   unsigned* __restrict__ done,
                                                   float* __restrict__ out) {
    int t = threadIdx.x;
    int lane = t & 63;
    int s = __builtin_amdgcn_readfirstlane(t >> 6);  // wave id == split id
    int c = blockIdx.x;

    __shared__ float s_m[NSPLIT], s_s[NSPLIT], s_v[NSPLIT];
    __shared__ int s_last;

    int cnt = counts[c];            // uniform -> scalar load
    if (cnt > 0) {
        int m = cnt < SLOTS ? cnt : SLOTS;
        const int* rl = lists + c * SLOTS;
        int slot = s * 256 + lane;

        float4 acc[4];
        #pragma unroll
        for (int j = 0; j < 4; ++j) acc[j] = make_float4(0.f, 0.f, 0.f, 0.f);

        if (m == 1)      gather4<1>(feat4, rl, m, slot, acc);
        else if (m == 2) gather4<2>(feat4, rl, m, slot, acc);
        else if (m <= 4) gather4<4>(feat4, rl, m, slot, acc);
        else {
            gather4<4>(feat4, rl, 4, slot, acc);
            for (int k = 4; k < m; ++k) {          // ~5% of classes (Poisson(2))
                size_t rb = (size_t)rl[k] * NF4 + slot;
                #pragma unroll
                for (int j = 0; j < 4; ++j) {
                    float4 v = feat4[rb + j * 64];
                    acc[j].x += v.x; acc[j].y += v.y; acc[j].z += v.z; acc[j].w += v.w;
                }
            }
        }

        float inv = 1.0f / (float)cnt;
        float4 mean[4];
        #pragma unroll
        for (int j = 0; j < 4; ++j) {
            mean[j].x = acc[j].x * inv; mean[j].y = acc[j].y * inv;
            mean[j].z = acc[j].z * inv; mean[j].w = acc[j].w * inv;
        }

        // wave max over this split's 1024 columns
        float M = -1e30f;
        #pragma unroll
        for (int j = 0; j < 4; ++j)
            M = fmaxf(M, fmaxf(fmaxf(mean[j].x, mean[j].y), fmaxf(mean[j].z, mean[j].w)));
        #pragma unroll
        for (int off = 1; off < 64; off <<= 1) M = fmaxf(M, __shfl_xor(M, off, 64));

        // wave sum of exp
        float S = 0.f;
        #pragma unroll
        for (int j = 0; j < 4; ++j)
            S += __expf(mean[j].x - M) + __expf(mean[j].y - M) +
                 __expf(mean[j].z - M) + __expf(mean[j].w - M);
        #pragma unroll
        for (int off = 1; off < 64; off <<= 1) S += __shfl_xor(S, off, 64);

        // v at column c: split c>>10, within-split float4 idx = (c>>2)&255,
        // owner lane = idx&63, j = idx>>6, component c&3. Static-index select
        // (cndmasks) to avoid scratch (runtime-indexed reg array).
        int sIdx = (c >> 2) & 255;
        int jj = sIdx >> 6, comp = c & 3;
        float cand = 0.f;
        #pragma unroll
        for (int j = 0; j < 4; ++j) {
            cand = (jj == j && comp == 0) ? mean[j].x : cand;
            cand = (jj == j && comp == 1) ? mean[j].y : cand;
            cand = (jj == j && comp == 2) ? mean[j].z : cand;
            cand = (jj == j && comp == 3) ? mean[j].w : cand;
        }
        float vcown = __shfl(cand, sIdx & 63, 64);
        float vc = (s == (c >> 10)) ? vcown : 0.f;

        if (lane == 0) { s_m[s] = M; s_s[s] = S; s_v[s] = vc; }
    }
    __syncthreads();

    // thread 0: exact LSE merge of the 4 splits -> contrib[c]; then signal.
    if (t == 0) {
        if (cnt > 0) {
            float M = s_m[0];
            #pragma unroll
            for (int j = 1; j < NSPLIT; ++j) M = fmaxf(M, s_m[j]);
            float S = 0.f, vc = 0.f;
            #pragma unroll
            for (int j = 0; j < NSPLIT; ++j) {
                S += s_s[j] * __expf(s_m[j] - M);
                vc += s_v[j];
            }
            contrib[c] = (float)cnt * (M + __logf(S) - vc);
        }
        __threadfence();                       // release contrib write
        unsigned old = atomicAdd(done, 1u);    // device-scope
        s_last = (old == (unsigned)(gridDim.x - 1)) ? 1 : 0;
    }
    __syncthreads();

    if (s_last) {
        __threadfence();                       // acquire side
        float sum = 0.f;
        for (int i = t; i < CC; i += BLK) {
            int cn = counts[i];                // pre-kernel data: plain load ok
            if (cn > 0)                        // agent-scope load: bypass stale L1
                sum += __hip_atomic_load(&contrib[i], __ATOMIC_RELAXED,
                                         __HIP_MEMORY_SCOPE_AGENT);
        }
        #pragma unroll
        for (int off = 1; off < 64; off <<= 1) sum += __shfl_xor(sum, off, 64);
        __shared__ float s_red[4];
        if (lane == 0) s_red[t >> 6] = sum;
        __syncthreads();
        if (t == 0)
            out[0] = (s_red[0] + s_red[1] + s_red[2] + s_red[3]) * SCALE;
    }
}

extern "C" void kernel_launch(void* const* d_in, const int* in_sizes, int n_in,
                              void* d_out, int out_size, void* d_ws, size_t ws_size,
                              hipStream_t stream) {
    const float* feat = (const float*)d_in[0];
    const int* label = (const int*)d_in[1];
    float* out = (float*)d_out;

    int* counts = (int*)d_ws;                      // CC ints
    int* lists = counts + CC;                      // CC * SLOTS ints
    float* contrib = (float*)(lists + CC * SLOTS); // CC floats
    unsigned* done = (unsigned*)(contrib + CC);    // 1 uint

    build_kernel<<<1, 1024, 0, stream>>>(label, counts, lists, done);
    part_kernel<<<CC, BLK, 0, stream>>>((const float4*)feat, counts, lists,
                                        contrib, done, out);
}

// Round 4
// 210.104 us; speedup vs baseline: 1.9170x; 1.9170x over previous
//
#include <hip/hip_runtime.h>
#include <math.h>

#define NN 8192
#define CC 4096
#define SLOTS 64
#define BLK 256
#define NSPLIT 4     // 4 column splits of 1024 cols (4 KB) per class; one WAVE per (class,split)
#define NF4 (CC / 4) // 1024 float4 per feature row

// out = sum_c cnt_c * value_c * NUM_POS / N^2 ; NUM_POS=4, N=8192
#define SCALE (4.0f / (8192.0f * 8192.0f))

// Fused init + index build: one block, counts histogram in LDS (16 KB),
// LDS atomics for slot assignment, then flush counts.
__global__ __launch_bounds__(1024) void build_kernel(const int* __restrict__ label,
                                                     int* __restrict__ counts,
                                                     int* __restrict__ lists) {
    __shared__ int s_cnt[CC];
    int t = threadIdx.x;
    #pragma unroll
    for (int i = t; i < CC; i += 1024) s_cnt[i] = 0;
    __syncthreads();
    #pragma unroll
    for (int i = t; i < NN; i += 1024) {
        int lab = label[i];
        int pos = atomicAdd(&s_cnt[lab], 1);
        if (pos < SLOTS) lists[lab * SLOTS + pos] = i;
    }
    __syncthreads();
    #pragma unroll
    for (int i = t; i < CC; i += 1024) counts[i] = s_cnt[i];
}

// Tiered gather: T rows x 4 float4 slots, all loads issued back-to-back
// (single vmcnt drain). Tail rows duplicate row 0 with weight 0 (dup loads
// hit L1 -- same addresses as k=0 -- ~free).
template <int T>
__device__ inline void gather4(const float4* __restrict__ feat4,
                               const int* __restrict__ rl, int m,
                               int slot, float4 acc[4]) {
    int r0 = rl[0];
    float4 v[T][4];
    #pragma unroll
    for (int k = 0; k < T; ++k) {
        int r = (k < m) ? rl[k] : r0;
        size_t rb = (size_t)r * NF4 + slot;
        #pragma unroll
        for (int j = 0; j < 4; ++j) v[k][j] = feat4[rb + j * 64];
    }
    #pragma unroll
    for (int k = 0; k < T; ++k) {
        float w = (k < m) ? 1.f : 0.f;
        #pragma unroll
        for (int j = 0; j < 4; ++j) {
            acc[j].x += w * v[k][j].x; acc[j].y += w * v[k][j].y;
            acc[j].z += w * v[k][j].z; acc[j].w += w * v[k][j].w;
        }
    }
}

// One block per class c; wave = split s (4 splits of 1024 cols). Lane l owns
// float4 slots s*256 + l + 64j (j=0..3): 4 coalesced 1 KB wave-loads per row,
// and the block's 4 waves together fetch each row as one 16 KB burst.
// Split-LSE merge = 3 scalars/wave through LDS; one contrib[c] written.
// NO device-scope fences / done-counters (round-3 post-mortem: ~230 us cost).
__global__ __launch_bounds__(BLK) void part_kernel(const float4* __restrict__ feat4,
                                                   const int* __restrict__ counts,
                                                   const int* __restrict__ lists,
                                                   float* __restrict__ contrib) {
    int t = threadIdx.x;
    int lane = t & 63;
    int s = __builtin_amdgcn_readfirstlane(t >> 6);  // wave id == split id
    int c = blockIdx.x;

    __shared__ float s_m[NSPLIT], s_s[NSPLIT], s_v[NSPLIT];

    int cnt = counts[c];            // uniform -> scalar load
    if (cnt == 0) {                 // block-uniform quick exit
        if (t == 0) contrib[c] = 0.f;
        return;
    }
    int m = cnt < SLOTS ? cnt : SLOTS;
    const int* rl = lists + c * SLOTS;
    int slot = s * 256 + lane;

    float4 acc[4];
    #pragma unroll
    for (int j = 0; j < 4; ++j) acc[j] = make_float4(0.f, 0.f, 0.f, 0.f);

    if (m == 1)      gather4<1>(feat4, rl, m, slot, acc);
    else if (m == 2) gather4<2>(feat4, rl, m, slot, acc);
    else if (m <= 4) gather4<4>(feat4, rl, m, slot, acc);
    else {
        gather4<4>(feat4, rl, 4, slot, acc);
        for (int k = 4; k < m; ++k) {          // ~5% of classes (Poisson(2))
            size_t rb = (size_t)rl[k] * NF4 + slot;
            #pragma unroll
            for (int j = 0; j < 4; ++j) {
                float4 v = feat4[rb + j * 64];
                acc[j].x += v.x; acc[j].y += v.y; acc[j].z += v.z; acc[j].w += v.w;
            }
        }
    }

    float inv = 1.0f / (float)cnt;
    float4 mean[4];
    #pragma unroll
    for (int j = 0; j < 4; ++j) {
        mean[j].x = acc[j].x * inv; mean[j].y = acc[j].y * inv;
        mean[j].z = acc[j].z * inv; mean[j].w = acc[j].w * inv;
    }

    // wave max over this split's 1024 columns
    float M = -1e30f;
    #pragma unroll
    for (int j = 0; j < 4; ++j)
        M = fmaxf(M, fmaxf(fmaxf(mean[j].x, mean[j].y), fmaxf(mean[j].z, mean[j].w)));
    #pragma unroll
    for (int off = 1; off < 64; off <<= 1) M = fmaxf(M, __shfl_xor(M, off, 64));

    // wave sum of exp
    float S = 0.f;
    #pragma unroll
    for (int j = 0; j < 4; ++j)
        S += __expf(mean[j].x - M) + __expf(mean[j].y - M) +
             __expf(mean[j].z - M) + __expf(mean[j].w - M);
    #pragma unroll
    for (int off = 1; off < 64; off <<= 1) S += __shfl_xor(S, off, 64);

    // v at column c: split c>>10, within-split float4 idx = (c>>2)&255,
    // owner lane = idx&63, j = idx>>6, component c&3. Static-index select
    // (cndmasks) to avoid scratch (runtime-indexed reg array).
    int sIdx = (c >> 2) & 255;
    int jj = sIdx >> 6, comp = c & 3;
    float cand = 0.f;
    #pragma unroll
    for (int j = 0; j < 4; ++j) {
        cand = (jj == j && comp == 0) ? mean[j].x : cand;
        cand = (jj == j && comp == 1) ? mean[j].y : cand;
        cand = (jj == j && comp == 2) ? mean[j].z : cand;
        cand = (jj == j && comp == 3) ? mean[j].w : cand;
    }
    float vcown = __shfl(cand, sIdx & 63, 64);
    float vc = (s == (c >> 10)) ? vcown : 0.f;

    if (lane == 0) { s_m[s] = M; s_s[s] = S; s_v[s] = vc; }
    __syncthreads();

    if (t == 0) {   // exact LSE merge of the 4 splits -> contrib[c]
        float Mt = s_m[0];
        #pragma unroll
        for (int j = 1; j < NSPLIT; ++j) Mt = fmaxf(Mt, s_m[j]);
        float St = 0.f, vct = 0.f;
        #pragma unroll
        for (int j = 0; j < NSPLIT; ++j) {
            St += s_s[j] * __expf(s_m[j] - Mt);
            vct += s_v[j];
        }
        contrib[c] = (float)cnt * (Mt + __logf(St) - vct);
    }
}

// Single block: reduce 4096 per-class contributions, write out[0] directly
// (no atomic, no output zero-init; cross-kernel visibility via dispatch edge).
__global__ __launch_bounds__(256) void finalize(const float* __restrict__ contrib,
                                                float* __restrict__ out) {
    float s = 0.f;
    for (int i = threadIdx.x; i < CC; i += 256) s += contrib[i];
    #pragma unroll
    for (int off = 1; off < 64; off <<= 1) s += __shfl_xor(s, off, 64);
    __shared__ float sr[4];
    int lane = threadIdx.x & 63, w = threadIdx.x >> 6;
    if (lane == 0) sr[w] = s;
    __syncthreads();
    if (threadIdx.x == 0) out[0] = (sr[0] + sr[1] + sr[2] + sr[3]) * SCALE;
}

extern "C" void kernel_launch(void* const* d_in, const int* in_sizes, int n_in,
                              void* d_out, int out_size, void* d_ws, size_t ws_size,
                              hipStream_t stream) {
    const float* feat = (const float*)d_in[0];
    const int* label = (const int*)d_in[1];
    float* out = (float*)d_out;

    int* counts = (int*)d_ws;                      // CC ints
    int* lists = counts + CC;                      // CC * SLOTS ints
    float* contrib = (float*)(lists + CC * SLOTS); // CC floats

    build_kernel<<<1, 1024, 0, stream>>>(label, counts, lists);
    part_kernel<<<CC, BLK, 0, stream>>>((const float4*)feat, counts, lists, contrib);
    finalize<<<1, 256, 0, stream>>>(contrib, out);
}

// Round 5
// 203.667 us; speedup vs baseline: 1.9776x; 1.0316x over previous
//
#include <hip/hip_runtime.h>
#include <math.h>

#define NN 8192
#define CC 4096
#define SLOTS 64
#define BLK 256
#define NSPLIT 4     // 4 column splits of 1024 cols (4 KB) per class; one WAVE per (class,split)
#define NF4 (CC / 4) // 1024 float4 per feature row

// out = sum_c cnt_c * value_c * NUM_POS / N^2 ; NUM_POS=4, N=8192
#define SCALE (4.0f / (8192.0f * 8192.0f))

// Grid-wide init + index build (measured-good R0 structure; the single-block
// fused variant serialized ~10 us on one CU -- round-4 post-mortem).
__global__ void init_kernel(int* __restrict__ counts) {
    int i = blockIdx.x * blockDim.x + threadIdx.x;
    if (i < CC) counts[i] = 0;
}

__global__ void build_index(const int* __restrict__ label,
                            int* __restrict__ counts,
                            int* __restrict__ lists) {
    int i = blockIdx.x * blockDim.x + threadIdx.x;
    if (i < NN) {
        int lab = label[i];
        int pos = atomicAdd(&counts[lab], 1);
        if (pos < SLOTS) lists[lab * SLOTS + pos] = i;
    }
}

// Tiered gather: T rows x 4 float4 slots, all loads issued back-to-back
// (single vmcnt drain). Tail rows duplicate row 0 with weight 0 (dup loads
// hit L1 -- same addresses as k=0 -- ~free).
template <int T>
__device__ inline void gather4(const float4* __restrict__ feat4,
                               const int* __restrict__ rl, int m,
                               int slot, float4 acc[4]) {
    int r0 = rl[0];
    float4 v[T][4];
    #pragma unroll
    for (int k = 0; k < T; ++k) {
        int r = (k < m) ? rl[k] : r0;
        size_t rb = (size_t)r * NF4 + slot;
        #pragma unroll
        for (int j = 0; j < 4; ++j) v[k][j] = feat4[rb + j * 64];
    }
    #pragma unroll
    for (int k = 0; k < T; ++k) {
        float w = (k < m) ? 1.f : 0.f;
        #pragma unroll
        for (int j = 0; j < 4; ++j) {
            acc[j].x += w * v[k][j].x; acc[j].y += w * v[k][j].y;
            acc[j].z += w * v[k][j].z; acc[j].w += w * v[k][j].w;
        }
    }
}

// One block per class c; wave = split s (4 splits of 1024 cols). Lane l owns
// float4 slots s*256 + l + 64j (j=0..3): 4 coalesced 1 KB wave-loads per row,
// and the block's 4 waves together fetch each row as one 16 KB burst.
// Split-LSE merge = 3 scalars/wave through LDS; one contrib[c] written.
// NO device-scope fences / done-counters (round-3 post-mortem: ~230 us cost).
__global__ __launch_bounds__(BLK) void part_kernel(const float4* __restrict__ feat4,
                                                   const int* __restrict__ counts,
                                                   const int* __restrict__ lists,
                                                   float* __restrict__ contrib) {
    int t = threadIdx.x;
    int lane = t & 63;
    int s = __builtin_amdgcn_readfirstlane(t >> 6);  // wave id == split id
    int c = blockIdx.x;

    __shared__ float s_m[NSPLIT], s_s[NSPLIT], s_v[NSPLIT];

    int cnt = counts[c];            // uniform -> scalar load
    if (cnt == 0) {                 // block-uniform quick exit
        if (t == 0) contrib[c] = 0.f;
        return;
    }
    int m = cnt < SLOTS ? cnt : SLOTS;
    const int* rl = lists + c * SLOTS;
    int slot = s * 256 + lane;

    float4 acc[4];
    #pragma unroll
    for (int j = 0; j < 4; ++j) acc[j] = make_float4(0.f, 0.f, 0.f, 0.f);

    if (m == 1)      gather4<1>(feat4, rl, m, slot, acc);
    else if (m == 2) gather4<2>(feat4, rl, m, slot, acc);
    else if (m <= 4) gather4<4>(feat4, rl, m, slot, acc);
    else {
        gather4<4>(feat4, rl, 4, slot, acc);
        for (int k = 4; k < m; ++k) {          // ~5% of classes (Poisson(2))
            size_t rb = (size_t)rl[k] * NF4 + slot;
            #pragma unroll
            for (int j = 0; j < 4; ++j) {
                float4 v = feat4[rb + j * 64];
                acc[j].x += v.x; acc[j].y += v.y; acc[j].z += v.z; acc[j].w += v.w;
            }
        }
    }

    float inv = 1.0f / (float)cnt;
    float4 mean[4];
    #pragma unroll
    for (int j = 0; j < 4; ++j) {
        mean[j].x = acc[j].x * inv; mean[j].y = acc[j].y * inv;
        mean[j].z = acc[j].z * inv; mean[j].w = acc[j].w * inv;
    }

    // wave max over this split's 1024 columns
    float M = -1e30f;
    #pragma unroll
    for (int j = 0; j < 4; ++j)
        M = fmaxf(M, fmaxf(fmaxf(mean[j].x, mean[j].y), fmaxf(mean[j].z, mean[j].w)));
    #pragma unroll
    for (int off = 1; off < 64; off <<= 1) M = fmaxf(M, __shfl_xor(M, off, 64));

    // wave sum of exp
    float S = 0.f;
    #pragma unroll
    for (int j = 0; j < 4; ++j)
        S += __expf(mean[j].x - M) + __expf(mean[j].y - M) +
             __expf(mean[j].z - M) + __expf(mean[j].w - M);
    #pragma unroll
    for (int off = 1; off < 64; off <<= 1) S += __shfl_xor(S, off, 64);

    // v at column c: split c>>10, within-split float4 idx = (c>>2)&255,
    // owner lane = idx&63, j = idx>>6, component c&3. Static-index select
    // (cndmasks) to avoid scratch (runtime-indexed reg array).
    int sIdx = (c >> 2) & 255;
    int jj = sIdx >> 6, comp = c & 3;
    float cand = 0.f;
    #pragma unroll
    for (int j = 0; j < 4; ++j) {
        cand = (jj == j && comp == 0) ? mean[j].x : cand;
        cand = (jj == j && comp == 1) ? mean[j].y : cand;
        cand = (jj == j && comp == 2) ? mean[j].z : cand;
        cand = (jj == j && comp == 3) ? mean[j].w : cand;
    }
    float vcown = __shfl(cand, sIdx & 63, 64);
    float vc = (s == (c >> 10)) ? vcown : 0.f;

    if (lane == 0) { s_m[s] = M; s_s[s] = S; s_v[s] = vc; }
    __syncthreads();

    if (t == 0) {   // exact LSE merge of the 4 splits -> contrib[c]
        float Mt = s_m[0];
        #pragma unroll
        for (int j = 1; j < NSPLIT; ++j) Mt = fmaxf(Mt, s_m[j]);
        float St = 0.f, vct = 0.f;
        #pragma unroll
        for (int j = 0; j < NSPLIT; ++j) {
            St += s_s[j] * __expf(s_m[j] - Mt);
            vct += s_v[j];
        }
        contrib[c] = (float)cnt * (Mt + __logf(St) - vct);
    }
}

// Single block: reduce 4096 per-class contributions, write out[0] directly
// (no atomic, no output zero-init; cross-kernel visibility via dispatch edge).
__global__ __launch_bounds__(256) void finalize(const float* __restrict__ contrib,
                                                float* __restrict__ out) {
    float s = 0.f;
    for (int i = threadIdx.x; i < CC; i += 256) s += contrib[i];
    #pragma unroll
    for (int off = 1; off < 64; off <<= 1) s += __shfl_xor(s, off, 64);
    __shared__ float sr[4];
    int lane = threadIdx.x & 63, w = threadIdx.x >> 6;
    if (lane == 0) sr[w] = s;
    __syncthreads();
    if (threadIdx.x == 0) out[0] = (sr[0] + sr[1] + sr[2] + sr[3]) * SCALE;
}

extern "C" void kernel_launch(void* const* d_in, const int* in_sizes, int n_in,
                              void* d_out, int out_size, void* d_ws, size_t ws_size,
                              hipStream_t stream) {
    const float* feat = (const float*)d_in[0];
    const int* label = (const int*)d_in[1];
    float* out = (float*)d_out;

    int* counts = (int*)d_ws;                      // CC ints
    int* lists = counts + CC;                      // CC * SLOTS ints
    float* contrib = (float*)(lists + CC * SLOTS); // CC floats

    init_kernel<<<(CC + BLK - 1) / BLK, BLK, 0, stream>>>(counts);
    build_index<<<(NN + BLK - 1) / BLK, BLK, 0, stream>>>(label, counts, lists);
    part_kernel<<<CC, BLK, 0, stream>>>((const float4*)feat, counts, lists, contrib);
    finalize<<<1, 256, 0, stream>>>(contrib, out);
}